// Round 11
// baseline (1788.431 us; speedup 1.0000x reference)
//
#include <hip/hip_runtime.h>

typedef __bf16 bf16;
typedef __bf16 bf16x8 __attribute__((ext_vector_type(8)));
typedef float  f32x4  __attribute__((ext_vector_type(4)));

// B=64, S=512, OBS=128, D=512, H=8, F=2048, L=4, A=16; rows M = B*513 = 32832
// R26 = R25 (best, 1774us) + gemm64 (BM=64) for FFN-down only:
//   FFN-down was grid (4,129)=516 blocks = 2.0/CU -- the most starved gemm
//   (~500us total).  gemm64: 64x128xBK32 tile, 4 waves x 32x64, acc[2][4]
//   (32 VGPR), dbuf 24KB LDS, R20 2-phase single-barrier schedule, same T2
//   swizzle + C/D mapping.  Grid (4,257)=1028 = 4/CU vs capacity ~5-6:
//   demand <= cap so the doubled residency is free (R20/R24 rule).
//   O-proj/embed stay on gemm128<SCHED=1> (BM=64 would put them at demand 8
//   > cap ~5, the R20 regression regime).  Everything else = R25.

__device__ __forceinline__ void cp16(const bf16* g, bf16* l)
{
    __builtin_amdgcn_global_load_lds(
        (const __attribute__((address_space(1))) void*)g,
        (__attribute__((address_space(3))) void*)l,
        16, 0, 0);
}

__global__ __launch_bounds__(256) void cvt_bf16(
    const float* __restrict__ src, bf16* __restrict__ dst, int n)
{
    for (int i = blockIdx.x * 256 + threadIdx.x; i < n; i += gridDim.x * 256)
        dst[i] = (bf16)src[i];
}

__global__ __launch_bounds__(256) void transpose_f32(
    const float* __restrict__ W, bf16* __restrict__ WT, int K, int N, long elemOff)
{
    __shared__ bf16 tile[32][33];
    const int bn = blockIdx.x * 32;
    const int bk = blockIdx.y * 32;
    const int tx = threadIdx.x & 31, ty = threadIdx.x >> 5;
    for (int r = 0; r < 32; r += 8)
        tile[ty + r][tx] = (bf16)W[elemOff + (long)(bk + ty + r) * N + (bn + tx)];
    __syncthreads();
    for (int r = 0; r < 32; r += 8)
        WT[(long)(bn + ty + r) * K + (bk + tx)] = tile[tx][ty + r];
}

// z=0..3 -> transpose 512x512 slice of {Wq,Wk,Wv,Wo}[layer] into
// {WqkvT+0, WqkvT+256K, WqkvT+512K, WoT}.
__global__ __launch_bounds__(256) void prep_qkvo(
    const float* __restrict__ Wq, const float* __restrict__ Wk,
    const float* __restrict__ Wv, const float* __restrict__ Wo,
    bf16* __restrict__ WqkvT, bf16* __restrict__ WoT, long elemOff)
{
    __shared__ bf16 tile[32][33];
    const int z = blockIdx.z;
    const float* W = (z == 0) ? Wq : (z == 1) ? Wk : (z == 2) ? Wv : Wo;
    bf16* WT = (z < 3) ? (WqkvT + (long)z * 262144) : WoT;
    const int bn = blockIdx.x * 32;
    const int bk = blockIdx.y * 32;
    const int tx = threadIdx.x & 31, ty = threadIdx.x >> 5;
    for (int r = 0; r < 32; r += 8)
        tile[ty + r][tx] = (bf16)W[elemOff + (long)(bk + ty + r) * 512 + (bn + tx)];
    __syncthreads();
    for (int r = 0; r < 32; r += 8)
        WT[(long)(bn + ty + r) * 512 + (bk + tx)] = tile[tx][ty + r];
}

// z=0: W1 [512][2048] -> W1T [2048][512];  z=1: W2 [2048][512] -> W2T [512][2048]
__global__ __launch_bounds__(256) void prep_ffn(
    const float* __restrict__ W1, const float* __restrict__ W2,
    bf16* __restrict__ W1T, bf16* __restrict__ W2T, long elemOff)
{
    __shared__ bf16 tile[32][33];
    const int z = blockIdx.z;
    const float* W = z ? W2 : W1;
    bf16* WT = z ? W2T : W1T;
    const int N = z ? 512 : 2048;
    const int K = z ? 2048 : 512;
    const int bn = (z ? blockIdx.y : blockIdx.x) * 32;
    const int bk = (z ? blockIdx.x : blockIdx.y) * 32;
    const int tx = threadIdx.x & 31, ty = threadIdx.x >> 5;
    for (int r = 0; r < 32; r += 8)
        tile[ty + r][tx] = (bf16)W[elemOff + (long)(bk + ty + r) * N + (bn + tx)];
    __syncthreads();
    for (int r = 0; r < 32; r += 8)
        WT[(long)(bn + ty + r) * K + (bk + tx)] = tile[tx][ty + r];
}

// all 4 layers' {bq,bk,bv} -> bqkv_all[l][1536] in one launch (24 blocks)
__global__ __launch_bounds__(256) void concat_all(
    const float* __restrict__ bq, const float* __restrict__ bk,
    const float* __restrict__ bv, float* __restrict__ dst)
{
    const int i = blockIdx.x * 256 + threadIdx.x;   // 0..6143
    if (i >= 6144) return;
    const int lay = i / 1536;
    const int rem = i - lay * 1536;
    float v;
    if (rem < 512)        v = bq[lay * 512 + rem];
    else if (rem < 1024)  v = bk[lay * 512 + rem - 512];
    else                  v = bv[lay * 512 + rem - 1024];
    dst[lay * 1536 + rem] = v;
}

__global__ __launch_bounds__(256) void build_x0(
    const float* __restrict__ hs, const int* __restrict__ resets,
    bf16* __restrict__ xb)
{
    const int b = blockIdx.x;
    const bool rz = (resets[b] != 0);
    const long base = (long)b * 513 * 512;
    for (int d = threadIdx.x; d < 512; d += 256)
        xb[base + d] = rz ? (bf16)0.f : (bf16)hs[b * 512 + d];
}

// GEMM: C[M,N] = A[M,K] @ BT[N,K]^T + bias(fp32).  128x128 tile, BK=32,
// 4 waves x (4x4) 16x16x32 MFMA, global_load_lds(16B) direct-to-LDS staging.
// LDS [128][32] linear dest; T2 XOR swizzle via pre-swizzled GLOBAL source
// (ksw) + swizzled read seg (qx).  N%128==0; M tail via overlap clamp.
// A row stride lda, C row stride ldc.  Bijective XCD swizzle.
// ROWMAP==1: row += row/512 + 1.  ACT: 0=none 1=relu 2=relu+eps 3=relu+eps iff col<1024.
// SCHED: 0 = single-buffer 2-barrier (R23); 1 = dbuf single-barrier 2-phase (R20).
template<int ROWMAP, int ACT, int SCHED>
__global__ __launch_bounds__(256) void gemm128(
    const bf16* __restrict__ A, const bf16* __restrict__ BT,
    const float* __restrict__ bias, bf16* __restrict__ outB,
    int M, int N, int K, int lda, int ldc)
{
    __shared__ bf16 As[(SCHED + 1) * 128 * 32];
    __shared__ bf16 Bs[(SCHED + 1) * 128 * 32];
    const int tid  = threadIdx.x;
    const int wave = tid >> 6;
    const int lane = tid & 63;
    const int q    = lane >> 4;
    const int lm   = lane & 15;
    const int wr   = wave >> 1, wc = wave & 1;

    // bijective XCD swizzle (m204): orig%8 = XCD slot -> contiguous partition
    int flat;
    {
        const int nwg  = gridDim.x * gridDim.y;
        const int orig = blockIdx.y * gridDim.x + blockIdx.x;
        const int qq = nwg >> 3, rr = nwg & 7;
        const int xcd = orig & 7, idx = orig >> 3;
        flat = (xcd < rr ? xcd * (qq + 1) : rr * (qq + 1) + (xcd - rr) * qq) + idx;
    }
    const int bx = flat % gridDim.x;
    const int by = flat / gridDim.x;
    int m0 = by * 128;
    if (m0 > M - 128) m0 = M - 128;            // tail overlap clamp
    const int n0 = bx * 128;

    // staging geometry: wave w issue i deposits rows w*32+i*16+(l>>2) at
    // linear LDS slot l (elem row*32 + (l&3)*8).  T2: lane fetches k-seg
    // (l&3)^((l>>2)&3) so physical (row,kp) holds logical kp^(row&3).
    const int r0  = wave * 32 + (lane >> 2);
    const int ksw = ((lane & 3) ^ ((lane >> 2) & 3)) * 8;
    const bf16* Ag0 = A  + (long)(m0 + r0) * lda + ksw;
    const bf16* Ag1 = A  + (long)(m0 + r0 + 16) * lda + ksw;
    const bf16* Bg0 = BT + (long)(n0 + r0) * K + ksw;
    const bf16* Bg1 = BT + (long)(n0 + r0 + 16) * K + ksw;

    // read-side swizzle: logical seg q lives at physical q^(row&3), row&3 = lm&3
    const int qx = (q ^ (lm & 3)) * 8;

    f32x4 acc[4][4];
    for (int i = 0; i < 4; i++) for (int j = 0; j < 4; j++)
        for (int r = 0; r < 4; r++) acc[i][j][r] = 0.f;

    if constexpr (SCHED == 0) {
        bf16* Al0 = As + wave * 1024;
        bf16* Al1 = As + wave * 1024 + 512;
        bf16* Bl0 = Bs + wave * 1024;
        bf16* Bl1 = Bs + wave * 1024 + 512;
        for (int k0 = 0; k0 < K; k0 += 32) {
            cp16(Ag0 + k0, Al0);
            cp16(Ag1 + k0, Al1);
            cp16(Bg0 + k0, Bl0);
            cp16(Bg1 + k0, Bl1);
            __syncthreads();                   // drains vmcnt -> DMA landed
            bf16x8 af[4], bfr[4];
            #pragma unroll
            for (int i = 0; i < 4; i++)
                af[i] = *(const bf16x8*)(As + (wr * 64 + i * 16 + lm) * 32 + qx);
            #pragma unroll
            for (int j = 0; j < 4; j++)
                bfr[j] = *(const bf16x8*)(Bs + (wc * 64 + j * 16 + lm) * 32 + qx);
            #pragma unroll
            for (int i = 0; i < 4; i++)
                #pragma unroll
                for (int j = 0; j < 4; j++)
                    acc[i][j] = __builtin_amdgcn_mfma_f32_16x16x32_bf16(
                        af[i], bfr[j], acc[i][j], 0, 0, 0);
            __syncthreads();                   // LDS safe for next DMA
        }
    } else {
        // R20 2-phase: STAGE(t+1) first, compute buf[cur], one barrier/iter.
        const int lb = wave * 1024;
        const int NT = K >> 5;
#define STAGE24(kt, buf)                                       \
        do {                                                   \
            const int _k0 = (kt) * 32;                         \
            cp16(Ag0 + _k0, &As[(buf) * 4096 + lb]);           \
            cp16(Ag1 + _k0, &As[(buf) * 4096 + lb + 512]);     \
            cp16(Bg0 + _k0, &Bs[(buf) * 4096 + lb]);           \
            cp16(Bg1 + _k0, &Bs[(buf) * 4096 + lb + 512]);     \
        } while (0)
        STAGE24(0, 0);
        asm volatile("s_waitcnt vmcnt(0)" ::: "memory");
        __builtin_amdgcn_s_barrier();
        int cur = 0;
        for (int t = 0; t < NT; ++t) {
            if (t + 1 < NT) STAGE24(t + 1, cur ^ 1);   // next-tile DMA FIRST
            bf16x8 af[4], bfr[4];
            #pragma unroll
            for (int i = 0; i < 4; i++)
                af[i] = *(const bf16x8*)(&As[cur * 4096 + (wr * 64 + i * 16 + lm) * 32 + qx]);
            #pragma unroll
            for (int j = 0; j < 4; j++)
                bfr[j] = *(const bf16x8*)(&Bs[cur * 4096 + (wc * 64 + j * 16 + lm) * 32 + qx]);
            #pragma unroll
            for (int i = 0; i < 4; i++)
                #pragma unroll
                for (int j = 0; j < 4; j++)
                    acc[i][j] = __builtin_amdgcn_mfma_f32_16x16x32_bf16(
                        af[i], bfr[j], acc[i][j], 0, 0, 0);
            asm volatile("s_waitcnt vmcnt(0)" ::: "memory");
            __builtin_amdgcn_s_barrier();
            cur ^= 1;
        }
#undef STAGE24
    }

    // C/D: col = lane&15, row = (lane>>4)*4 + r  [session-verified]
    #pragma unroll
    for (int j = 0; j < 4; j++) {
        const int col = n0 + wc * 64 + j * 16 + lm;
        const float bv = bias[col];
        #pragma unroll
        for (int i = 0; i < 4; i++) {
            #pragma unroll
            for (int r = 0; r < 4; r++) {
                int row = m0 + wr * 64 + i * 16 + q * 4 + r;
                float vv = acc[i][j][r] + bv;
                if (ACT == 1) vv = fmaxf(vv, 0.f);
                if (ACT == 2) vv = fmaxf(vv, 0.f) + 1e-3f;
                if (ACT == 3 && col < 1024) vv = fmaxf(vv, 0.f) + 1e-3f;
                if (ROWMAP == 1) row = row + (row >> 9) + 1;
                outB[(long)row * ldc + col] = (bf16)vv;
            }
        }
    }
}

// gemm64: BM=64 variant for grid-starved long-K gemms (FFN-down).
// 64x128xBK32 tile, 4 waves x (2x4) 16x16x32 MFMA (wave-tile 32x64),
// acc[2][4], dbuf 24KB LDS, R20 2-phase single-barrier schedule, same T2
// swizzle (row&3 == lm&3 holds) and C/D mapping as gemm128.
template<int ACT>
__global__ __launch_bounds__(256) void gemm64(
    const bf16* __restrict__ A, const bf16* __restrict__ BT,
    const float* __restrict__ bias, bf16* __restrict__ outB,
    int M, int N, int K, int lda, int ldc)
{
    __shared__ bf16 As[2][64 * 32];    // 8KB
    __shared__ bf16 Bs[2][128 * 32];   // 16KB
    const int tid  = threadIdx.x;
    const int wave = tid >> 6;
    const int lane = tid & 63;
    const int q    = lane >> 4;
    const int lm   = lane & 15;
    const int wr   = wave >> 1, wc = wave & 1;   // wave-tile 32 rows x 64 cols

    int flat;
    {
        const int nwg  = gridDim.x * gridDim.y;
        const int orig = blockIdx.y * gridDim.x + blockIdx.x;
        const int qq = nwg >> 3, rr = nwg & 7;
        const int xcd = orig & 7, idx = orig >> 3;
        flat = (xcd < rr ? xcd * (qq + 1) : rr * (qq + 1) + (xcd - rr) * qq) + idx;
    }
    const int bx = flat % gridDim.x;
    const int by = flat / gridDim.x;
    int m0 = by * 64;
    if (m0 > M - 64) m0 = M - 64;              // tail overlap clamp
    const int n0 = bx * 128;

    // staging: A wave w stages rows w*16+(l>>2) at elem w*512 + l*8 (linear);
    // B same geometry as gemm128 (rows w*32+(l>>2), +16).
    const int ksw = ((lane & 3) ^ ((lane >> 2) & 3)) * 8;
    const bf16* AgA = A  + (long)(m0 + wave * 16 + (lane >> 2)) * lda + ksw;
    const bf16* Bg0 = BT + (long)(n0 + wave * 32 + (lane >> 2)) * K + ksw;
    const bf16* Bg1 = BT + (long)(n0 + wave * 32 + (lane >> 2) + 16) * K + ksw;
    const int qx = (q ^ (lm & 3)) * 8;

    f32x4 acc[2][4];
    for (int i = 0; i < 2; i++) for (int j = 0; j < 4; j++)
        for (int r = 0; r < 4; r++) acc[i][j][r] = 0.f;

    const int NT = K >> 5;
#define STAGE64(kt, buf)                                       \
    do {                                                       \
        const int _k0 = (kt) * 32;                             \
        cp16(AgA + _k0, &As[(buf)][wave * 512]);               \
        cp16(Bg0 + _k0, &Bs[(buf)][wave * 1024]);              \
        cp16(Bg1 + _k0, &Bs[(buf)][wave * 1024 + 512]);        \
    } while (0)
    STAGE64(0, 0);
    asm volatile("s_waitcnt vmcnt(0)" ::: "memory");
    __builtin_amdgcn_s_barrier();
    int cur = 0;
    for (int t = 0; t < NT; ++t) {
        if (t + 1 < NT) STAGE64(t + 1, cur ^ 1);   // next-tile DMA FIRST
        bf16x8 af[2], bfr[4];
        #pragma unroll
        for (int i = 0; i < 2; i++)
            af[i] = *(const bf16x8*)(&As[cur][(wr * 32 + i * 16 + lm) * 32 + qx]);
        #pragma unroll
        for (int j = 0; j < 4; j++)
            bfr[j] = *(const bf16x8*)(&Bs[cur][(wc * 64 + j * 16 + lm) * 32 + qx]);
        #pragma unroll
        for (int i = 0; i < 2; i++)
            #pragma unroll
            for (int j = 0; j < 4; j++)
                acc[i][j] = __builtin_amdgcn_mfma_f32_16x16x32_bf16(
                    af[i], bfr[j], acc[i][j], 0, 0, 0);
        asm volatile("s_waitcnt vmcnt(0)" ::: "memory");
        __builtin_amdgcn_s_barrier();
        cur ^= 1;
    }
#undef STAGE64

    // C/D: col = lane&15, row = (lane>>4)*4 + r
    #pragma unroll
    for (int j = 0; j < 4; j++) {
        const int col = n0 + wc * 64 + j * 16 + lm;
        const float bv = bias[col];
        #pragma unroll
        for (int i = 0; i < 2; i++) {
            #pragma unroll
            for (int r = 0; r < 4; r++) {
                const int row = m0 + wr * 32 + i * 16 + q * 4 + r;
                float vv = acc[i][j][r] + bv;
                if (ACT == 1) vv = fmaxf(vv, 0.f);
                outB[(long)row * ldc + col] = (bf16)vv;
            }
        }
    }
}

// FAVOR+ attention, full MFMA.  Reads pq/pk/vv as column slices {0,512,1024}
// of the strided qkv[row][1536] buffer; writes ao back into the pq slice
// (per-(b,h) alias safe: each t8 tile's pq rows are staged before overwrite).
// R25: pass-1 staging vectorized (16B loads, paired 4B transposed writes,
// register ksum + one-time LDS atomicAdd).  LDS layout/MFMA unchanged.
#define FP 72
__global__ __launch_bounds__(256) void favor_mfma(bf16* qkv)
{
    const int bh = blockIdx.x;
    const int b = bh >> 3, h = bh & 7;
    const long rbQ = (long)b * 513 * 1536 + h * 64;
    const long rbK = rbQ + 512;
    const long rbV = rbQ + 1024;

    __shared__ bf16 pkT[64][FP];
    __shared__ bf16 vT [64][FP];
    __shared__ bf16 kvT[64][FP];
    __shared__ bf16 pqS[64][FP];
    __shared__ float ksumS[64];
    __shared__ float denS[64];

    const int tid  = threadIdx.x;
    const int wave = tid >> 6;
    const int lane = tid & 63;
    const int q    = lane >> 4;
    const int lm   = lane & 15;
    const int wr   = wave >> 1, wc = wave & 1;

    if (tid < 64) ksumS[tid] = 0.f;

    // pass-1 staging map: thread -> rows {2*r2, 2*r2+1}, d-seg dseg..dseg+7
    const int r2   = tid >> 3;          // 0..31
    const int dseg = (tid & 7) * 8;     // 0..56
    const int ra   = 2 * r2;

    float ks8[8];
    #pragma unroll
    for (int e = 0; e < 8; e++) ks8[e] = 0.f;

    f32x4 akv[2][2];
    for (int i = 0; i < 2; i++) for (int j = 0; j < 2; j++)
        for (int r = 0; r < 4; r++) akv[i][j][r] = 0.f;

    for (int t8 = 0; t8 < 9; t8++) {
        const int s0 = t8 * 64;
        const int ga = s0 + ra;
        const int gb = ga + 1;
        bf16x8 pka, pkb, va, vb;
        if (ga < 513) {
            pka = *(const bf16x8*)(qkv + rbK + (long)ga * 1536 + dseg);
            va  = *(const bf16x8*)(qkv + rbV + (long)ga * 1536 + dseg);
        } else {
            #pragma unroll
            for (int e = 0; e < 8; e++) { pka[e] = (bf16)0.f; va[e] = (bf16)0.f; }
        }
        if (gb < 513) {
            pkb = *(const bf16x8*)(qkv + rbK + (long)gb * 1536 + dseg);
            vb  = *(const bf16x8*)(qkv + rbV + (long)gb * 1536 + dseg);
        } else {
            #pragma unroll
            for (int e = 0; e < 8; e++) { pkb[e] = (bf16)0.f; vb[e] = (bf16)0.f; }
        }
        #pragma unroll
        for (int e = 0; e < 8; e++) {
            union { unsigned u; bf16 h[2]; } pw, vw2;
            pw.h[0]  = pka[e]; pw.h[1]  = pkb[e];
            vw2.h[0] = va[e];  vw2.h[1] = vb[e];
            *(unsigned*)&pkT[dseg + e][ra] = pw.u;    // 4B aligned: 144k+4*r2
            *(unsigned*)&vT [dseg + e][ra] = vw2.u;
            ks8[e] += (float)pka[e] + (float)pkb[e];
        }
        __syncthreads();
        #pragma unroll
        for (int ks = 0; ks < 2; ks++) {
            bf16x8 a0 = *(const bf16x8*)(&pkT[wr * 32 + lm     ][ks * 32 + q * 8]);
            bf16x8 a1 = *(const bf16x8*)(&pkT[wr * 32 + 16 + lm][ks * 32 + q * 8]);
            bf16x8 b0 = *(const bf16x8*)(&vT [wc * 32 + lm     ][ks * 32 + q * 8]);
            bf16x8 b1 = *(const bf16x8*)(&vT [wc * 32 + 16 + lm][ks * 32 + q * 8]);
            akv[0][0] = __builtin_amdgcn_mfma_f32_16x16x32_bf16(a0, b0, akv[0][0], 0, 0, 0);
            akv[0][1] = __builtin_amdgcn_mfma_f32_16x16x32_bf16(a0, b1, akv[0][1], 0, 0, 0);
            akv[1][0] = __builtin_amdgcn_mfma_f32_16x16x32_bf16(a1, b0, akv[1][0], 0, 0, 0);
            akv[1][1] = __builtin_amdgcn_mfma_f32_16x16x32_bf16(a1, b1, akv[1][1], 0, 0, 0);
        }
        __syncthreads();
    }
    #pragma unroll
    for (int e = 0; e < 8; e++)
        atomicAdd(&ksumS[dseg + e], ks8[e]);
    #pragma unroll
    for (int i = 0; i < 2; i++)
        #pragma unroll
        for (int j = 0; j < 2; j++)
            #pragma unroll
            for (int r = 0; r < 4; r++)
                kvT[wc * 32 + j * 16 + lm][wr * 32 + i * 16 + q * 4 + r] =
                    (bf16)akv[i][j][r];
    __syncthreads();

    const int prow = tid >> 2;
    const int pseg = (tid & 3) * 16;
    for (int t8 = 0; t8 < 9; t8++) {
        const int s0 = t8 * 64;
        const int gs = s0 + prow;
        if (gs < 513) {
            *(bf16x8*)(&pqS[prow][pseg])     = *(const bf16x8*)(qkv + rbQ + (long)gs * 1536 + pseg);
            *(bf16x8*)(&pqS[prow][pseg + 8]) = *(const bf16x8*)(qkv + rbQ + (long)gs * 1536 + pseg + 8);
        } else {
            bf16x8 z;
            for (int r = 0; r < 8; r++) z[r] = (bf16)0.f;
            *(bf16x8*)(&pqS[prow][pseg])     = z;
            *(bf16x8*)(&pqS[prow][pseg + 8]) = z;
        }
        __syncthreads();
        {
            const int s = tid >> 2, mb = (tid & 3) * 16;
            float dp = 0.f;
            #pragma unroll
            for (int m2 = 0; m2 < 16; m2++)
                dp += (float)pqS[s][mb + m2] * ksumS[mb + m2];
            dp += __shfl_xor(dp, 1);
            dp += __shfl_xor(dp, 2);
            if ((tid & 3) == 0) denS[s] = dp;
        }
        __syncthreads();
        f32x4 an[4];
        for (int j = 0; j < 4; j++)
            for (int r = 0; r < 4; r++) an[j][r] = 0.f;
        #pragma unroll
        for (int ks = 0; ks < 2; ks++) {
            bf16x8 a = *(const bf16x8*)(&pqS[wave * 16 + lm][ks * 32 + q * 8]);
            #pragma unroll
            for (int j = 0; j < 4; j++) {
                bf16x8 bb = *(const bf16x8*)(&kvT[j * 16 + lm][ks * 32 + q * 8]);
                an[j] = __builtin_amdgcn_mfma_f32_16x16x32_bf16(a, bb, an[j], 0, 0, 0);
            }
        }
        #pragma unroll
        for (int j = 0; j < 4; j++) {
            #pragma unroll
            for (int r = 0; r < 4; r++) {
                const int sl  = wave * 16 + q * 4 + r;
                const int gs2 = s0 + sl;
                if (gs2 < 513) {
                    const int d = j * 16 + lm;
                    qkv[rbQ + (long)gs2 * 1536 + d] = (bf16)(an[j][r] / denS[sl]);
                }
            }
        }
        __syncthreads();
    }
}

__global__ __launch_bounds__(256) void ln_res(
    const bf16* __restrict__ y, int ldy, const float* __restrict__ sc,
    const float* __restrict__ bi, bf16* __restrict__ xb)
{
    const int row  = blockIdx.x * 4 + (threadIdx.x >> 6);
    const int lane = threadIdx.x & 63;
    const bf16* yr = y  + (long)row * ldy + lane * 8;
    bf16*       xr = xb + (long)row * 512 + lane * 8;
    bf16x8 yv = *(const bf16x8*)yr;
    bf16x8 xv = *(const bf16x8*)xr;
    float v[8];
    float sum = 0.f;
    #pragma unroll
    for (int i = 0; i < 8; i++) { v[i] = (float)yv[i] + (float)xv[i]; sum += v[i]; }
    #pragma unroll
    for (int o = 32; o; o >>= 1) sum += __shfl_xor(sum, o);
    const float mean = sum * (1.f / 512.f);
    float vs = 0.f;
    #pragma unroll
    for (int i = 0; i < 8; i++) { float dd = v[i] - mean; vs += dd * dd; }
    #pragma unroll
    for (int o = 32; o; o >>= 1) vs += __shfl_xor(vs, o);
    const float rstd = rsqrtf(vs * (1.f / 512.f) + 1e-6f);
    bf16x8 ov;
    #pragma unroll
    for (int i = 0; i < 8; i++)
        ov[i] = (bf16)((v[i] - mean) * rstd * sc[lane * 8 + i] + bi[lane * 8 + i]);
    *(bf16x8*)xr = ov;
}

__global__ __launch_bounds__(256) void final_head(
    const bf16* __restrict__ xb, const float* __restrict__ Wqp,
    const float* __restrict__ bqp, float* __restrict__ out)
{
    const int b = blockIdx.x;
    const bf16* xr = xb + (long)b * 513 * 512;
    for (int i = threadIdx.x; i < 512; i += 256) out[b * 512 + i] = (float)xr[i];
    const int a = threadIdx.x & 15, g = threadIdx.x >> 4;
    float p = 0.f;
    for (int k = g * 32; k < g * 32 + 32; k++)
        p += (float)xr[k] * Wqp[k * 16 + a];
    __shared__ float red[256];
    red[threadIdx.x] = p;
    __syncthreads();
    if (threadIdx.x < 16) {
        float s = bqp[a];
        for (int g2 = 0; g2 < 16; g2++) s += red[g2 * 16 + a];
        out[64 * 512 + b * 16 + a] = s;
    }
}

extern "C" void kernel_launch(void* const* d_in, const int* in_sizes, int n_in,
                              void* d_out, int out_size, void* d_ws, size_t ws_size,
                              hipStream_t stream)
{
    (void)in_sizes; (void)n_in; (void)out_size; (void)ws_size;
    const float* hs    = (const float*)d_in[0];
    const float* ins   = (const float*)d_in[1];
    const int*   resets= (const int*)d_in[2];
    const float* W_emb = (const float*)d_in[3];
    const float* b_emb = (const float*)d_in[4];
    const float* Wq    = (const float*)d_in[5];
    const float* bq    = (const float*)d_in[6];
    const float* Wk    = (const float*)d_in[7];
    const float* bk    = (const float*)d_in[8];
    const float* Wv    = (const float*)d_in[9];
    const float* bv    = (const float*)d_in[10];
    const float* Wo    = (const float*)d_in[11];
    const float* bo    = (const float*)d_in[12];
    const float* ln1s  = (const float*)d_in[13];
    const float* ln1b  = (const float*)d_in[14];
    const float* ln2s  = (const float*)d_in[15];
    const float* ln2b  = (const float*)d_in[16];
    const float* W1    = (const float*)d_in[17];
    const float* b1    = (const float*)d_in[18];
    const float* W2    = (const float*)d_in[19];
    const float* b2    = (const float*)d_in[20];
    const float* Wqp   = (const float*)d_in[21];
    const float* bqp   = (const float*)d_in[22];
    float* out = (float*)d_out;
    char* ws  = (char*)d_ws;

    // ---- workspace layout (bytes), peak ~149.30 MB ----
    // xb   [32832][512]  bf16   @ 0            (33,619,968)
    // qkv  [32832][1536] bf16   @ 33,619,968   (100,859,904)
    //   f  [16416][2048] bf16   @ qkv+0        (67,239,936)   (FFN, qkv dead)
    //   y2 [32832][512]  bf16   @ qkv+67,239,936 (33,619,968) (exact fit)
    // WembT               @ 134,479,872  (131,072)  -> reused as bqkv_all after embed
    // LW                  @ 134,610,944: WqkvT(1,572,864) WoT(524,288)
    //                       W1T(2,097,152) W2T(2,097,152)
    // insb                @ 140,908,544  (8,388,608)  -> end 149,297,152
    bf16* xb   = (bf16*)(ws);
    bf16* qkv  = (bf16*)(ws + 33619968);
    bf16* f    = qkv;
    bf16* y2   = (bf16*)(ws + 33619968 + 67239936);
    bf16* WembT= (bf16*)(ws + 134479872);
    float* bqkv_all = (float*)(ws + 134479872);   // 24KB, reuses WembT after embed
    char* LW   = ws + 134610944;
    bf16* WqkvT= (bf16*)(LW + 0);
    bf16* WoT  = (bf16*)(LW + 1572864);
    bf16* W1T  = (bf16*)(LW + 2097152);
    bf16* W2T  = (bf16*)(LW + 4194304);
    bf16* insb = (bf16*)(ws + 140908544);

    cvt_bf16<<<4096, 256, 0, stream>>>(ins, insb, 4194304);
    transpose_f32<<<dim3(16, 4), 256, 0, stream>>>(W_emb, WembT, 128, 512, 0);
    build_x0<<<64, 256, 0, stream>>>(hs, resets, xb);
    gemm128<1, 0, 1><<<dim3(4, 256), 256, 0, stream>>>(
        insb, WembT, b_emb, xb, 32768, 512, 128, 128, 512);
    // WembT dead from here; bqkv_all takes the region
    concat_all<<<24, 256, 0, stream>>>(bq, bk, bv, bqkv_all);

    for (int l = 0; l < 4; l++) {
        const long o512  = (long)l * 262144;
        const long o2048 = (long)l * 1048576;
        prep_qkvo<<<dim3(16, 16, 4), 256, 0, stream>>>(Wq, Wk, Wv, Wo, WqkvT, WoT, o512);
        prep_ffn<<<dim3(64, 16, 2), 256, 0, stream>>>(W1, W2, W1T, W2T, o2048);

        // fused QKV (demand 12 blocks/CU -> SCHED=0 keeps TLP)
        gemm128<0, 3, 0><<<dim3(12, 257), 256, 0, stream>>>(
            xb, WqkvT, bqkv_all + l * 1536, qkv, 32832, 1536, 512, 512, 1536);
        favor_mfma<<<512, 256, 0, stream>>>(qkv);
        // O-proj (demand 4/CU <= 5-block cap -> SCHED=1 pipeline, free)
        gemm128<0, 0, 1><<<dim3(4, 257), 256, 0, stream>>>(
            qkv, WoT, bo + l * 512, qkv + 512, 32832, 512, 512, 1536, 1536);
        ln_res<<<8208, 256, 0, stream>>>(qkv + 512, 1536, ln1s + l * 512, ln1b + l * 512, xb);

        // FFN in two 16416-row chunks; f + y2 alias exactly inside qkv region
        for (int c = 0; c < 2; c++) {
            const long r0 = (long)c * 16416;
            // up: demand 8/CU -> SCHED=0
            gemm128<0, 1, 0><<<dim3(16, 129), 256, 0, stream>>>(
                xb + r0 * 512, W1T, b1 + l * 2048, f, 16416, 2048, 512, 512, 2048);
            // down: K=2048, was 2 blocks/CU -> gemm64 (BM=64): 4/CU, free
            gemm64<0><<<dim3(4, 257), 256, 0, stream>>>(
                f, W2T, b2 + l * 512, y2 + r0 * 512, 16416, 512, 2048, 2048, 512);
        }
        ln_res<<<8208, 256, 0, stream>>>(y2, 512, ln2s + l * 512, ln2b + l * 512, xb);
    }

    final_head<<<64, 256, 0, stream>>>(xb, Wqp, bqp, out);
}